// Round 9
// baseline (3285.182 us; speedup 1.0000x reference)
//
#include <hip/hip_runtime.h>

typedef short v8s __attribute__((ext_vector_type(8)));
typedef float v4f __attribute__((ext_vector_type(4)));

constexpr int H_ = 1024, B_ = 64, T_ = 512;
constexpr int RPITCH = 17;
constexpr int BH = B_ * H_;   // u32 elements per h buffer
constexpr int CGQ = 2;        // col-tiles per agate block (fused path)

static __device__ __forceinline__ float bf2f(unsigned short u) {
    unsigned v = ((unsigned)u) << 16;
    return __builtin_bit_cast(float, v);
}
static __device__ __forceinline__ unsigned short f2bf(float f) {
    unsigned u = __builtin_bit_cast(unsigned, f);
    u += 0x7fffu + ((u >> 16) & 1u);
    return (unsigned short)(u >> 16);
}

// ws layout (ushort units unless noted):
//   h packed (u32, FRAGMENT-ORDERED): [2][B*H] u32
//     off(rg,c,q,m,j) = (((rg*32 + c)*4 + q)*16 + m)*8 + j
constexpr size_t WOFF_HPK = 0;                             // u32 area, 2*BH u32
constexpr size_t WOFF_WHI = 4u * B_ * H_;                  // [4][1024][1024] W hi (ushort)
constexpr size_t WOFF_WLO = WOFF_WHI + 4u * 1024 * 1024;   // [4][1024][1024] W lo (ushort)
constexpr size_t WOFF_SYNC = WOFF_WLO + 4u * 1024 * 1024;  // u32 sync area (1024 u32)
// sync: per-rg step counters split 8 ways: (rg,c) at u32 index (rg*8+c)*32.
// (fallback path uses (rg*4+c)*32 — disjoint init, both zeroed.)
constexpr size_t WOFF_FLAGS = WOFF_SYNC + 2048;            // u32 axflag[1024] (fused path)
constexpr size_t WOFF_AX = WOFF_FLAGS + 2048;              // f32 area: AX[T][B][H]
constexpr size_t NEED_AX_BYTES = WOFF_AX * 2 + (size_t)T_ * B_ * H_ * 4;  // ~151.5 MB

// stage fp32 weights as bf16 hi/lo pairs (gate order: Wmu, Wgmu, Wga, Wa)
__global__ __launch_bounds__(256)
void conv_w_kernel(const float* __restrict__ Wmu, const float* __restrict__ Wgmu,
                   const float* __restrict__ Wga, const float* __restrict__ Wa,
                   unsigned short* __restrict__ ws)
{
    const float* src[4] = { Wmu, Wgmu, Wga, Wa };
    unsigned idx = blockIdx.x * 256 + threadIdx.x;   // [0, 4M)
    unsigned g = idx >> 20, rem = idx & 0xFFFFFu;
    float v = src[g][rem];
    unsigned short hi = f2bf(v);
    unsigned short lo = f2bf(v - bf2f(hi));
    ws[WOFF_WHI + idx] = hi;
    ws[WOFF_WLO + idx] = lo;
}

__global__ __launch_bounds__(256)
void init_h_kernel(unsigned short* __restrict__ ws)
{
    unsigned gid = blockIdx.x * 256 + threadIdx.x;   // 256 blocks -> 65536 threads
    unsigned* hpk = (unsigned*)(ws + WOFF_HPK);
    hpk[gid] = 0u;
    hpk[gid + (unsigned)BH] = 0u;
    unsigned* syncp = (unsigned*)(ws + WOFF_SYNC);
    if (gid < 2048u) syncp[gid] = 0u;   // step counters + axflags
}

__global__ __launch_bounds__(256)
void sentinel_kernel(float* __restrict__ out, float val, int n)
{
    int gid = blockIdx.x * 256 + threadIdx.x;
    if (gid < n) out[gid] = val;
}

// ---------------- FUSED persistent kernel ----------------
// Grid 1280 x 256. bids 0..255: persist role (dispatched first -> co-resident;
// step barrier per rg). bids 256..1279: agate role (CGQ=2), computes AX for one
// (chunk,rg,cg-pair) and publishes an axflag. Persist gates on the flag once per
// 64 steps. One-way dependency + __launch_bounds__(256,2) (>=2 blocks/CU by
// contract) => deadlock-free under any dispatch order.
__global__ __launch_bounds__(256, 2)
void plasdyn_fused(const float* __restrict__ xv,
                   const float* __restrict__ Bmu, const float* __restrict__ Bgmu,
                   const float* __restrict__ Bga, const float* __restrict__ Ba,
                   float* __restrict__ out, unsigned short* __restrict__ ws)
{
    __shared__ float smem[4 * 3 * 16 * RPITCH];   // persist: red[4][3][16][RPITCH]; agate: red3[2][4][16*RPITCH]

    const int tid = threadIdx.x, bid = blockIdx.x;
    const int wave = tid >> 6, lane = tid & 63;
    const int m = lane & 15, quad = lane >> 4;
    const int kbase = wave * 256;
    const int row = tid >> 4, col = tid & 15;

    unsigned* hpk = (unsigned*)(ws + WOFF_HPK);
    unsigned* syncp = (unsigned*)(ws + WOFF_SYNC);
    unsigned* axflag = (unsigned*)(ws + WOFF_FLAGS);
    unsigned* axu = (unsigned*)(ws + WOFF_AX);     // AX as u32 bits (agent-scope coherent)

    if (bid >= 256) {
        // ================= agate role =================
        const int a = bid - 256;                  // 0..1023
        const int combo = a >> 5;                 // 0..31
        const int cgh = a & 31;                   // 0..31
        const int chunk = combo >> 2, rg = combo & 3;
        const int cg0 = cgh * CGQ;
        const int rowbase = rg * 16;
        const int rowm = rowbase + m;
        const int grow = rowbase + row;

        v8s wh3[CGQ][8], wl3[CGQ][8];
        #pragma unroll
        for (int c = 0; c < CGQ; ++c) {
            const int colbase = (cg0 + c) * 16;
            const unsigned short* ph = ws + WOFF_WHI + ((size_t)(3 * 1024 + colbase + m) << 10) + kbase;
            const unsigned short* pl = ws + WOFF_WLO + ((size_t)(3 * 1024 + colbase + m) << 10) + kbase;
            #pragma unroll
            for (int s = 0; s < 8; ++s) {
                wh3[c][s] = *(const v8s*)(ph + s * 32 + quad * 8);
                wl3[c][s] = *(const v8s*)(pl + s * 32 + quad * 8);
            }
        }

        const int t0 = chunk * 64;
        float4 xf[16];
        {
            const float* xr0 = xv + ((size_t)rowm * T_ + t0) * H_;
            #pragma unroll
            for (int s = 0; s < 8; ++s) {
                const int k0 = kbase + s * 32 + quad * 8;
                xf[2 * s]     = *(const float4*)(xr0 + k0);
                xf[2 * s + 1] = *(const float4*)(xr0 + k0 + 4);
            }
        }

        for (int tt = 0; tt < 64; ++tt) {
            const int t = t0 + tt;
            const int tn = (tt < 63) ? (t + 1) : t;
            const float* xrn = xv + ((size_t)rowm * T_ + tn) * H_;

            v4f a0 = {0,0,0,0}, a1 = {0,0,0,0};

            #pragma unroll
            for (int s = 0; s < 8; ++s) {
                const int k0 = kbase + s * 32 + quad * 8;
                float4 f0 = xf[2 * s];
                float4 f1 = xf[2 * s + 1];
                float fv[8] = { f0.x, f0.y, f0.z, f0.w, f1.x, f1.y, f1.z, f1.w };
                v8s xh, xl;
                #pragma unroll
                for (int j = 0; j < 8; ++j) {
                    unsigned short hb = f2bf(fv[j]);
                    xh[j] = (short)hb;
                    xl[j] = (short)f2bf(fv[j] - bf2f(hb));
                }
                // per-accumulator chain identical to baseline: xh@wh, xl@wh, xh@wl
                a0 = __builtin_amdgcn_mfma_f32_16x16x32_bf16(xh, wh3[0][s], a0, 0, 0, 0);
                a0 = __builtin_amdgcn_mfma_f32_16x16x32_bf16(xl, wh3[0][s], a0, 0, 0, 0);
                a0 = __builtin_amdgcn_mfma_f32_16x16x32_bf16(xh, wl3[0][s], a0, 0, 0, 0);
                a1 = __builtin_amdgcn_mfma_f32_16x16x32_bf16(xh, wh3[1][s], a1, 0, 0, 0);
                a1 = __builtin_amdgcn_mfma_f32_16x16x32_bf16(xl, wh3[1][s], a1, 0, 0, 0);
                a1 = __builtin_amdgcn_mfma_f32_16x16x32_bf16(xh, wl3[1][s], a1, 0, 0, 0);

                xf[2 * s]     = *(const float4*)(xrn + k0);
                xf[2 * s + 1] = *(const float4*)(xrn + k0 + 4);
            }

            __syncthreads();   // previous iteration's combine reads are done
            #pragma unroll
            for (int r = 0; r < 4; ++r) {
                const int rr = (quad * 4 + r) * RPITCH + m;
                smem[(0 * 4 + wave) * (16 * RPITCH) + rr] = a0[r];
                smem[(1 * 4 + wave) * (16 * RPITCH) + rr] = a1[r];
            }
            __syncthreads();

            #pragma unroll
            for (int c = 0; c < CGQ; ++c) {
                float z3 = 0.f;
                #pragma unroll
                for (int w = 0; w < 4; ++w)
                    z3 += smem[(c * 4 + w) * (16 * RPITCH) + row * RPITCH + col];
                __hip_atomic_store(&axu[((size_t)t * B_ + grow) * H_ + (cg0 + c) * 16 + col],
                                   __builtin_bit_cast(unsigned, z3),
                                   __ATOMIC_RELAXED, __HIP_MEMORY_SCOPE_AGENT);
            }
        }

        // publish: __syncthreads drains all waves' AX stores (vmcnt 0), then flag.
        __syncthreads();
        if (tid == 0)
            __hip_atomic_store(&axflag[a], 1u, __ATOMIC_RELAXED, __HIP_MEMORY_SCOPE_AGENT);
        return;
    }

    // ================= persist role (round-6 proven core) =================
    const int cg = bid & 63;
    const int colbase = cg * 16;
    const int rg = bid >> 6;
    const int rowbase = rg * 16;

    v8s wh[3][8], wl[3][8];
    #pragma unroll
    for (int g = 0; g < 3; ++g) {
        const unsigned short* ph = ws + WOFF_WHI + ((size_t)(g * 1024 + colbase + m) << 10) + kbase;
        const unsigned short* pl = ws + WOFF_WLO + ((size_t)(g * 1024 + colbase + m) << 10) + kbase;
        #pragma unroll
        for (int s = 0; s < 8; ++s) {
            wh[g][s] = *(const v8s*)(ph + s * 32 + quad * 8);
            wl[g][s] = *(const v8s*)(pl + s * 32 + quad * 8);
        }
    }

    const int gcol = colbase + col;
    const int grow = rowbase + row;
    const float bmu = Bmu[gcol], bgmu = Bgmu[gcol], bga = Bga[gcol], ba = Ba[gcol];
    const int w_off = (((rg * 32 + (gcol >> 5)) * 4 + ((gcol >> 3) & 3)) * 16 + row) * 8 + (gcol & 7);
    const int fragbase_u32 = (rg * 32 + wave * 8) * 512 + lane * 8;

    unsigned* mycnt = &syncp[(rg * 8 + (cg & 7)) * 32];
    float* red = smem;

    for (int t = 0; t < T_; ++t) {
        const int cur = t & 1, nxt = cur ^ 1;
        const unsigned long long* h64 = (const unsigned long long*)(hpk + cur * BH);
        const size_t axidx = ((size_t)t * B_ + grow) * H_ + gcol;

        float axv;
        if ((t & 63) != 0) {
            // chunk already gated at the last multiple of 64 -> safe to prefetch
            axv = __builtin_bit_cast(float,
                __hip_atomic_load(&axu[axidx], __ATOMIC_RELAXED, __HIP_MEMORY_SCOPE_AGENT));
        }

        // ---- gates: chunk flag (once per 64 steps) + step barrier ----
        if (tid == 0) {
            if ((t & 63) == 0) {
                const unsigned fidx = (unsigned)((((t >> 6) * 4 + rg) << 5) + (cg >> 1));
                while (__hip_atomic_load(&axflag[fidx], __ATOMIC_RELAXED,
                                         __HIP_MEMORY_SCOPE_AGENT) == 0u)
                    __builtin_amdgcn_s_sleep(1);
            }
            if (t != 0) {
                const unsigned target = 8u * (unsigned)t;
                for (;;) {
                    bool ok = true;
                    #pragma unroll
                    for (int c = 0; c < 8; ++c) {
                        unsigned v = __hip_atomic_load(&syncp[(rg * 8 + c) * 32],
                                                       __ATOMIC_RELAXED, __HIP_MEMORY_SCOPE_AGENT);
                        ok &= (v >= target);
                    }
                    if (ok) break;
                    __builtin_amdgcn_s_sleep(1);
                }
            }
        }
        __syncthreads();

        if ((t & 63) == 0) {
            axv = __builtin_bit_cast(float,
                __hip_atomic_load(&axu[axidx], __ATOMIC_RELAXED, __HIP_MEMORY_SCOPE_AGENT));
        }

        // ---- h-dependent gates (mu, gmu, ga) ----
        v4f acc0 = {0,0,0,0}, acc1 = {0,0,0,0}, acc2 = {0,0,0,0};

        #pragma unroll
        for (int s = 0; s < 8; ++s) {
            const int b64 = (fragbase_u32 + s * 512) >> 1;
            unsigned long long hq0 = __hip_atomic_load(h64 + b64 + 0, __ATOMIC_RELAXED, __HIP_MEMORY_SCOPE_AGENT);
            unsigned long long hq1 = __hip_atomic_load(h64 + b64 + 1, __ATOMIC_RELAXED, __HIP_MEMORY_SCOPE_AGENT);
            unsigned long long hq2 = __hip_atomic_load(h64 + b64 + 2, __ATOMIC_RELAXED, __HIP_MEMORY_SCOPE_AGENT);
            unsigned long long hq3 = __hip_atomic_load(h64 + b64 + 3, __ATOMIC_RELAXED, __HIP_MEMORY_SCOPE_AGENT);
            unsigned hu[8];
            hu[0] = (unsigned)hq0; hu[1] = (unsigned)(hq0 >> 32);
            hu[2] = (unsigned)hq1; hu[3] = (unsigned)(hq1 >> 32);
            hu[4] = (unsigned)hq2; hu[5] = (unsigned)(hq2 >> 32);
            hu[6] = (unsigned)hq3; hu[7] = (unsigned)(hq3 >> 32);
            v8s ahi, alo;
            #pragma unroll
            for (int j = 0; j < 8; ++j) {
                ahi[j] = (short)(hu[j] >> 16);
                alo[j] = (short)(hu[j] & 0xFFFFu);
            }

            acc0 = __builtin_amdgcn_mfma_f32_16x16x32_bf16(ahi, wh[0][s], acc0, 0, 0, 0);
            acc1 = __builtin_amdgcn_mfma_f32_16x16x32_bf16(ahi, wh[1][s], acc1, 0, 0, 0);
            acc2 = __builtin_amdgcn_mfma_f32_16x16x32_bf16(ahi, wh[2][s], acc2, 0, 0, 0);
            acc0 = __builtin_amdgcn_mfma_f32_16x16x32_bf16(alo, wh[0][s], acc0, 0, 0, 0);
            acc1 = __builtin_amdgcn_mfma_f32_16x16x32_bf16(alo, wh[1][s], acc1, 0, 0, 0);
            acc2 = __builtin_amdgcn_mfma_f32_16x16x32_bf16(alo, wh[2][s], acc2, 0, 0, 0);
            acc0 = __builtin_amdgcn_mfma_f32_16x16x32_bf16(ahi, wl[0][s], acc0, 0, 0, 0);
            acc1 = __builtin_amdgcn_mfma_f32_16x16x32_bf16(ahi, wl[1][s], acc1, 0, 0, 0);
            acc2 = __builtin_amdgcn_mfma_f32_16x16x32_bf16(ahi, wl[2][s], acc2, 0, 0, 0);
        }

        {
            float* rw = red + wave * (3 * 16 * RPITCH);
            #pragma unroll
            for (int r = 0; r < 4; ++r) {
                int rr = quad * 4 + r;
                rw[(0 * 16 + rr) * RPITCH + m] = acc0[r];
                rw[(1 * 16 + rr) * RPITCH + m] = acc1[r];
                rw[(2 * 16 + rr) * RPITCH + m] = acc2[r];
            }
        }
        __syncthreads();

        {
            float z0 = 0.f, z1 = 0.f, z2 = 0.f;
            #pragma unroll
            for (int w = 0; w < 4; ++w) {
                const float* rr = red + w * (3 * 16 * RPITCH);
                z0 += rr[(0 * 16 + row) * RPITCH + col];
                z1 += rr[(1 * 16 + row) * RPITCH + col];
                z2 += rr[(2 * 16 + row) * RPITCH + col];
            }
            float z3 = axv;   // computed identically in the agate role
            z0 += bmu; z1 += bgmu; z2 += bga; z3 += ba;
            const float s1 = 1.0f / (1.0f + __expf(-z1));
            const float s2 = 1.0f / (1.0f + __expf(-z2));
            float hval = z0 * s1 + z3 * s2;
            hval = fminf(fmaxf(hval, -64.0f), 64.0f);   // NaN-squash safety

            const unsigned short hi16 = f2bf(hval);
            const unsigned short lo16 = f2bf(hval - bf2f(hi16));
            const unsigned pk = ((unsigned)hi16 << 16) | (unsigned)lo16;
            __hip_atomic_store(hpk + nxt * BH + w_off, pk,
                               __ATOMIC_RELAXED, __HIP_MEMORY_SCOPE_AGENT);
            if (t == T_ - 1) out[(size_t)grow * H_ + gcol] = hval;   // FP32 output
        }

        // drain h stores (vmcnt(0) in __syncthreads), then publish arrival.
        __syncthreads();
        if (t != T_ - 1 && tid == 0)
            __hip_atomic_fetch_add(mycnt, 1u, __ATOMIC_RELAXED, __HIP_MEMORY_SCOPE_AGENT);
    }
}

// ---------------- fallback (round-5 kernel, used if ws too small) ----------------
__global__ __launch_bounds__(256, 1)
void plasdyn_persist_fb(const float* __restrict__ xv,
                        const float* __restrict__ Bmu, const float* __restrict__ Bgmu,
                        const float* __restrict__ Bga, const float* __restrict__ Ba,
                        float* __restrict__ out, unsigned short* __restrict__ ws)
{
    __shared__ float red[4 * 3 * 16 * RPITCH];
    __shared__ float red3[4 * 16 * RPITCH];

    const int tid = threadIdx.x, bid = blockIdx.x;
    const int cg = bid & 63;
    const int colbase = cg * 16;
    const int rg = bid >> 6;
    const int rowbase = rg * 16;
    const int wave = tid >> 6, lane = tid & 63;
    const int m = lane & 15, quad = lane >> 4;
    const int kbase = wave * 256;
    const int rowm = rowbase + m;

    unsigned* hpk = (unsigned*)(ws + WOFF_HPK);
    unsigned* syncp = (unsigned*)(ws + WOFF_SYNC);

    v8s wh[4][8], wl[4][8];
    #pragma unroll
    for (int g = 0; g < 4; ++g) {
        const unsigned short* ph = ws + WOFF_WHI + ((size_t)(g * 1024 + colbase + m) << 10) + kbase;
        const unsigned short* pl = ws + WOFF_WLO + ((size_t)(g * 1024 + colbase + m) << 10) + kbase;
        #pragma unroll
        for (int s = 0; s < 8; ++s) {
            wh[g][s] = *(const v8s*)(ph + s * 32 + quad * 8);
            wl[g][s] = *(const v8s*)(pl + s * 32 + quad * 8);
        }
    }

    const int row = tid >> 4, col = tid & 15;
    const int gcol = colbase + col;
    const int grow = rowbase + row;
    const float bmu = Bmu[gcol], bgmu = Bgmu[gcol], bga = Bga[gcol], ba = Ba[gcol];
    const int w_off = (((rg * 32 + (gcol >> 5)) * 4 + ((gcol >> 3) & 3)) * 16 + row) * 8 + (gcol & 7);
    const int fragbase_u32 = (rg * 32 + wave * 8) * 512 + lane * 8;

    unsigned* mycnt = &syncp[(rg * 4 + (cg & 3)) * 32];
    unsigned* c0 = &syncp[(rg * 4 + 0) * 32];
    unsigned* c1 = &syncp[(rg * 4 + 1) * 32];
    unsigned* c2 = &syncp[(rg * 4 + 2) * 32];
    unsigned* c3 = &syncp[(rg * 4 + 3) * 32];

    float4 xf[16];
    auto phaseB = [&](const float* xrp) {
        v4f a3 = {0,0,0,0};
        #pragma unroll
        for (int s = 0; s < 8; ++s) {
            const int k0 = kbase + s * 32 + quad * 8;
            float4 f0 = xf[2 * s];
            float4 f1 = xf[2 * s + 1];
            float fv[8] = { f0.x, f0.y, f0.z, f0.w, f1.x, f1.y, f1.z, f1.w };
            v8s xh, xl;
            #pragma unroll
            for (int j = 0; j < 8; ++j) {
                unsigned short hb = f2bf(fv[j]);
                xh[j] = (short)hb;
                xl[j] = (short)f2bf(fv[j] - bf2f(hb));
            }
            a3 = __builtin_amdgcn_mfma_f32_16x16x32_bf16(xh, wh[3][s], a3, 0, 0, 0);
            a3 = __builtin_amdgcn_mfma_f32_16x16x32_bf16(xl, wh[3][s], a3, 0, 0, 0);
            a3 = __builtin_amdgcn_mfma_f32_16x16x32_bf16(xh, wl[3][s], a3, 0, 0, 0);
            xf[2 * s]     = *(const float4*)(xrp + k0);
            xf[2 * s + 1] = *(const float4*)(xrp + k0 + 4);
        }
        float* rw3 = red3 + wave * (16 * RPITCH);
        #pragma unroll
        for (int r = 0; r < 4; ++r)
            rw3[(quad * 4 + r) * RPITCH + m] = a3[r];
    };

    {
        const float* xr0 = xv + ((size_t)rowm * T_ + 0) * H_;
        #pragma unroll
        for (int s = 0; s < 8; ++s) {
            const int k0 = kbase + s * 32 + quad * 8;
            xf[2 * s]     = *(const float4*)(xr0 + k0);
            xf[2 * s + 1] = *(const float4*)(xr0 + k0 + 4);
        }
        const float* xr1 = xv + ((size_t)rowm * T_ + (T_ > 1 ? 1 : 0)) * H_;
        phaseB(xr1);
    }

    for (int t = 0; t < T_; ++t) {
        const int cur = t & 1, nxt = cur ^ 1;
        const unsigned long long* h64 = (const unsigned long long*)(hpk + cur * BH);

        if (t != 0) {
            if (tid == 0) {
                const unsigned target = 16u * (unsigned)t;
                for (;;) {
                    unsigned a = __hip_atomic_load(c0, __ATOMIC_RELAXED, __HIP_MEMORY_SCOPE_AGENT);
                    unsigned b = __hip_atomic_load(c1, __ATOMIC_RELAXED, __HIP_MEMORY_SCOPE_AGENT);
                    unsigned c = __hip_atomic_load(c2, __ATOMIC_RELAXED, __HIP_MEMORY_SCOPE_AGENT);
                    unsigned d = __hip_atomic_load(c3, __ATOMIC_RELAXED, __HIP_MEMORY_SCOPE_AGENT);
                    if (a >= target && b >= target && c >= target && d >= target) break;
                    __builtin_amdgcn_s_sleep(1);
                }
            }
            __syncthreads();
        }

        v4f acc0 = {0,0,0,0}, acc1 = {0,0,0,0}, acc2 = {0,0,0,0};

        #pragma unroll
        for (int s = 0; s < 8; ++s) {
            const int b64 = (fragbase_u32 + s * 512) >> 1;
            unsigned long long hq0 = __hip_atomic_load(h64 + b64 + 0, __ATOMIC_RELAXED, __HIP_MEMORY_SCOPE_AGENT);
            unsigned long long hq1 = __hip_atomic_load(h64 + b64 + 1, __ATOMIC_RELAXED, __HIP_MEMORY_SCOPE_AGENT);
            unsigned long long hq2 = __hip_atomic_load(h64 + b64 + 2, __ATOMIC_RELAXED, __HIP_MEMORY_SCOPE_AGENT);
            unsigned long long hq3 = __hip_atomic_load(h64 + b64 + 3, __ATOMIC_RELAXED, __HIP_MEMORY_SCOPE_AGENT);
            unsigned hu[8];
            hu[0] = (unsigned)hq0; hu[1] = (unsigned)(hq0 >> 32);
            hu[2] = (unsigned)hq1; hu[3] = (unsigned)(hq1 >> 32);
            hu[4] = (unsigned)hq2; hu[5] = (unsigned)(hq2 >> 32);
            hu[6] = (unsigned)hq3; hu[7] = (unsigned)(hq3 >> 32);
            v8s ahi, alo;
            #pragma unroll
            for (int j = 0; j < 8; ++j) {
                ahi[j] = (short)(hu[j] >> 16);
                alo[j] = (short)(hu[j] & 0xFFFFu);
            }

            acc0 = __builtin_amdgcn_mfma_f32_16x16x32_bf16(ahi, wh[0][s], acc0, 0, 0, 0);
            acc1 = __builtin_amdgcn_mfma_f32_16x16x32_bf16(ahi, wh[1][s], acc1, 0, 0, 0);
            acc2 = __builtin_amdgcn_mfma_f32_16x16x32_bf16(ahi, wh[2][s], acc2, 0, 0, 0);
            acc0 = __builtin_amdgcn_mfma_f32_16x16x32_bf16(alo, wh[0][s], acc0, 0, 0, 0);
            acc1 = __builtin_amdgcn_mfma_f32_16x16x32_bf16(alo, wh[1][s], acc1, 0, 0, 0);
            acc2 = __builtin_amdgcn_mfma_f32_16x16x32_bf16(alo, wh[2][s], acc2, 0, 0, 0);
            acc0 = __builtin_amdgcn_mfma_f32_16x16x32_bf16(ahi, wl[0][s], acc0, 0, 0, 0);
            acc1 = __builtin_amdgcn_mfma_f32_16x16x32_bf16(ahi, wl[1][s], acc1, 0, 0, 0);
            acc2 = __builtin_amdgcn_mfma_f32_16x16x32_bf16(ahi, wl[2][s], acc2, 0, 0, 0);
        }

        {
            float* rw = red + wave * (3 * 16 * RPITCH);
            #pragma unroll
            for (int r = 0; r < 4; ++r) {
                int rr = quad * 4 + r;
                rw[(0 * 16 + rr) * RPITCH + m] = acc0[r];
                rw[(1 * 16 + rr) * RPITCH + m] = acc1[r];
                rw[(2 * 16 + rr) * RPITCH + m] = acc2[r];
            }
        }
        __syncthreads();

        {
            float z0 = 0.f, z1 = 0.f, z2 = 0.f, z3 = 0.f;
            #pragma unroll
            for (int w = 0; w < 4; ++w) {
                const float* rr = red + w * (3 * 16 * RPITCH);
                z0 += rr[(0 * 16 + row) * RPITCH + col];
                z1 += rr[(1 * 16 + row) * RPITCH + col];
                z2 += rr[(2 * 16 + row) * RPITCH + col];
                z3 += red3[w * (16 * RPITCH) + row * RPITCH + col];
            }
            z0 += bmu; z1 += bgmu; z2 += bga; z3 += ba;
            const float s1 = 1.0f / (1.0f + __expf(-z1));
            const float s2 = 1.0f / (1.0f + __expf(-z2));
            float hval = z0 * s1 + z3 * s2;
            hval = fminf(fmaxf(hval, -64.0f), 64.0f);

            const unsigned short hi16 = f2bf(hval);
            const unsigned short lo16 = f2bf(hval - bf2f(hi16));
            const unsigned pk = ((unsigned)hi16 << 16) | (unsigned)lo16;
            __hip_atomic_store(hpk + nxt * BH + w_off, pk,
                               __ATOMIC_RELAXED, __HIP_MEMORY_SCOPE_AGENT);
            if (t == T_ - 1) out[(size_t)grow * H_ + gcol] = hval;
        }

        __syncthreads();
        if (t != T_ - 1) {
            if (tid == 0)
                __hip_atomic_fetch_add(mycnt, 1u, __ATOMIC_RELAXED, __HIP_MEMORY_SCOPE_AGENT);
            const int tp = (t + 2 < T_) ? (t + 2) : (T_ - 1);
            phaseB(xv + ((size_t)rowm * T_ + tp) * H_);
        }
    }
}

extern "C" void kernel_launch(void* const* d_in, const int* in_sizes, int n_in,
                              void* d_out, int out_size, void* d_ws, size_t ws_size,
                              hipStream_t stream)
{
    float* out = (float*)d_out;
    unsigned short* ws = (unsigned short*)d_ws;

    const int SZ_X = B_ * T_ * H_;
    const int SZ_W = H_ * H_;
    const int SZ_B = H_;

    bool dict_pat = (n_in == 9 &&
        in_sizes[0] == SZ_X &&
        in_sizes[1] == SZ_W && in_sizes[3] == SZ_W && in_sizes[5] == SZ_W && in_sizes[7] == SZ_W &&
        in_sizes[2] == SZ_B && in_sizes[4] == SZ_B && in_sizes[6] == SZ_B && in_sizes[8] == SZ_B);

    if (!dict_pat) {
        hipLaunchKernelGGL(sentinel_kernel, dim3((out_size + 255) / 256), dim3(256), 0, stream,
                           out, 2000.0f, out_size);
        return;
    }

    // dict order: x, W_mu, b_mu, Wg_mu, bg_mu, W_a, b_a, Wg_a, bg_a  (all fp32)
    const float* x    = (const float*)d_in[0];
    const float* Wmu  = (const float*)d_in[1];
    const float* bmu  = (const float*)d_in[2];
    const float* Wgmu = (const float*)d_in[3];
    const float* bgmu = (const float*)d_in[4];
    const float* Wa   = (const float*)d_in[5];
    const float* ba   = (const float*)d_in[6];
    const float* Wga  = (const float*)d_in[7];
    const float* bga  = (const float*)d_in[8];

    hipLaunchKernelGGL(conv_w_kernel, dim3(16384), dim3(256), 0, stream,
                       Wmu, Wgmu, Wga, Wa, ws);
    hipLaunchKernelGGL(init_h_kernel, dim3(256), dim3(256), 0, stream, ws);

    if (ws_size >= NEED_AX_BYTES) {
        // fused: 256 persist blocks (dispatched first, co-resident) + 1024 agate
        // producer blocks filling the second block-slot per CU.
        hipLaunchKernelGGL(plasdyn_fused, dim3(1280), dim3(256), 0, stream,
                           x, bmu, bgmu, bga, ba, out, ws);
    } else {
        hipLaunchKernelGGL(plasdyn_persist_fb, dim3(256), dim3(256), 0, stream,
                           x, bmu, bgmu, bga, ba, out, ws);
    }
}

// Round 10
// 2692.608 us; speedup vs baseline: 1.2201x; 1.2201x over previous
//
#include <hip/hip_runtime.h>

typedef short v8s __attribute__((ext_vector_type(8)));
typedef float v4f __attribute__((ext_vector_type(4)));

constexpr int H_ = 1024, B_ = 64, T_ = 512;
constexpr int RPITCH = 17;
constexpr int BH = B_ * H_;   // u32 elements per h buffer
constexpr int CGQ = 4;        // col-tiles per agate block

static __device__ __forceinline__ float bf2f(unsigned short u) {
    unsigned v = ((unsigned)u) << 16;
    return __builtin_bit_cast(float, v);
}
static __device__ __forceinline__ unsigned short f2bf(float f) {
    unsigned u = __builtin_bit_cast(unsigned, f);
    u += 0x7fffu + ((u >> 16) & 1u);
    return (unsigned short)(u >> 16);
}

// ws layout (ushort units unless noted):
//   h packed (u32, FRAGMENT-ORDERED): [2][B*H] u32
//     off(rg,c,q,m,j) = (((rg*32 + c)*4 + q)*16 + m)*8 + j
constexpr size_t WOFF_HPK = 0;                             // u32 area, 2*BH u32
constexpr size_t WOFF_WHI = 4u * B_ * H_;                  // [4][1024][1024] W hi (ushort)
constexpr size_t WOFF_WLO = WOFF_WHI + 4u * 1024 * 1024;   // [4][1024][1024] W lo (ushort)
constexpr size_t WOFF_SYNC = WOFF_WLO + 4u * 1024 * 1024;  // u32 sync area (1024 u32)
// sync (fast path): per-rg arrival counters split 8 ways: counter (rg,c) at u32
// index (rg*8+c)*32 (own 128B line); per-BLOCK bump by blocks with cg&7==c.
// (fallback path uses (rg*4+c)*32.)
constexpr size_t WOFF_AX = WOFF_SYNC + 2048;               // f32 area: AX[T][B][H] (fast path)
constexpr size_t NEED_AX_BYTES = WOFF_AX * 2 + (size_t)T_ * B_ * H_ * 4;  // ~151.5 MB

// stage fp32 weights as bf16 hi/lo pairs (gate order: Wmu, Wgmu, Wga, Wa)
__global__ __launch_bounds__(256)
void conv_w_kernel(const float* __restrict__ Wmu, const float* __restrict__ Wgmu,
                   const float* __restrict__ Wga, const float* __restrict__ Wa,
                   unsigned short* __restrict__ ws)
{
    const float* src[4] = { Wmu, Wgmu, Wga, Wa };
    unsigned idx = blockIdx.x * 256 + threadIdx.x;   // [0, 4M)
    unsigned g = idx >> 20, rem = idx & 0xFFFFFu;
    float v = src[g][rem];
    unsigned short hi = f2bf(v);
    unsigned short lo = f2bf(v - bf2f(hi));
    ws[WOFF_WHI + idx] = hi;
    ws[WOFF_WLO + idx] = lo;
}

__global__ __launch_bounds__(256)
void init_h_kernel(unsigned short* __restrict__ ws)
{
    unsigned gid = blockIdx.x * 256 + threadIdx.x;   // 256 blocks -> 65536 threads
    unsigned* hpk = (unsigned*)(ws + WOFF_HPK);
    hpk[gid] = 0u;
    hpk[gid + (unsigned)BH] = 0u;
    unsigned* syncp = (unsigned*)(ws + WOFF_SYNC);
    if (gid < 1024u) syncp[gid] = 0u;
}

__global__ __launch_bounds__(256)
void sentinel_kernel(float* __restrict__ out, float val, int n)
{
    int gid = blockIdx.x * 256 + threadIdx.x;
    if (gid < n) out[gid] = val;
}

// ---------------- fast path: precompute the a-gate for ALL t ----------------
// AX[t][b][col] with the bit-identical per-tile chain. CGQ=4: x loaded+converted
// once per fragment, fed to 4 reg-pinned weight tiles. XCD-AWARE MAPPING: the 16
// blocks sharing one (chunk,rg) x-slice (4 MB) are placed on ONE XCD (bid%8 ->
// XCD round-robin; 2 slices x 16 blocks = 32 blocks fill an XCD's 32 CUs at
// 1 block/CU), so the 16x x-reuse is served from that XCD's 4 MB L2 instead of
// the LLC. Pure index bijection - per-block work and numerics untouched.
__global__ __launch_bounds__(256)
void agate_pre(const float* __restrict__ xv, unsigned short* __restrict__ ws)
{
    __shared__ float red3[CGQ][4][16 * RPITCH];   // [cg][wave][row*RPITCH+col]

    const int tid = threadIdx.x, bid = blockIdx.x;
    const int xcd = bid & 7;                     // dispatch: bid%8 -> XCD
    const int j = bid >> 3;                      // 0..63
    const int combo = xcd + 8 * (j >> 4);        // 0..31 = (chunk,rg); 4 combos/XCD
    const int cgq = j & 15;                      // 0..15
    const int chunk = combo >> 2, rg = combo & 3;
    const int cg0 = cgq * CGQ;
    const int rowbase = rg * 16;
    const int wave = tid >> 6, lane = tid & 63;
    const int m = lane & 15, quad = lane >> 4;
    const int kbase = wave * 256;
    const int rowm = rowbase + m;

    // weights for 4 col-tiles, pinned in regs (static indexing everywhere)
    v8s wh3[CGQ][8], wl3[CGQ][8];
    #pragma unroll
    for (int c = 0; c < CGQ; ++c) {
        const int colbase = (cg0 + c) * 16;
        const unsigned short* ph = ws + WOFF_WHI + ((size_t)(3 * 1024 + colbase + m) << 10) + kbase;
        const unsigned short* pl = ws + WOFF_WLO + ((size_t)(3 * 1024 + colbase + m) << 10) + kbase;
        #pragma unroll
        for (int s = 0; s < 8; ++s) {
            wh3[c][s] = *(const v8s*)(ph + s * 32 + quad * 8);
            wl3[c][s] = *(const v8s*)(pl + s * 32 + quad * 8);
        }
    }

    const int row = tid >> 4, col = tid & 15;
    const int grow = rowbase + row;
    float* ax = (float*)(ws + WOFF_AX);

    const int t0 = chunk * 64;
    float4 xf[16];
    {
        const float* xr0 = xv + ((size_t)rowm * T_ + t0) * H_;
        #pragma unroll
        for (int s = 0; s < 8; ++s) {
            const int k0 = kbase + s * 32 + quad * 8;
            xf[2 * s]     = *(const float4*)(xr0 + k0);
            xf[2 * s + 1] = *(const float4*)(xr0 + k0 + 4);
        }
    }

    for (int tt = 0; tt < 64; ++tt) {
        const int t = t0 + tt;
        const int tn = (tt < 63) ? (t + 1) : t;
        const float* xrn = xv + ((size_t)rowm * T_ + tn) * H_;

        v4f a0 = {0,0,0,0}, a1 = {0,0,0,0}, a2 = {0,0,0,0}, a3v = {0,0,0,0};

        #pragma unroll
        for (int s = 0; s < 8; ++s) {
            const int k0 = kbase + s * 32 + quad * 8;
            float4 f0 = xf[2 * s];
            float4 f1 = xf[2 * s + 1];
            float fv[8] = { f0.x, f0.y, f0.z, f0.w, f1.x, f1.y, f1.z, f1.w };
            v8s xh, xl;
            #pragma unroll
            for (int j2 = 0; j2 < 8; ++j2) {
                unsigned short hb = f2bf(fv[j2]);
                xh[j2] = (short)hb;
                xl[j2] = (short)f2bf(fv[j2] - bf2f(hb));
            }
            // per-accumulator chain identical to baseline: xh@wh, xl@wh, xh@wl
            a0  = __builtin_amdgcn_mfma_f32_16x16x32_bf16(xh, wh3[0][s], a0, 0, 0, 0);
            a0  = __builtin_amdgcn_mfma_f32_16x16x32_bf16(xl, wh3[0][s], a0, 0, 0, 0);
            a0  = __builtin_amdgcn_mfma_f32_16x16x32_bf16(xh, wl3[0][s], a0, 0, 0, 0);
            a1  = __builtin_amdgcn_mfma_f32_16x16x32_bf16(xh, wh3[1][s], a1, 0, 0, 0);
            a1  = __builtin_amdgcn_mfma_f32_16x16x32_bf16(xl, wh3[1][s], a1, 0, 0, 0);
            a1  = __builtin_amdgcn_mfma_f32_16x16x32_bf16(xh, wl3[1][s], a1, 0, 0, 0);
            a2  = __builtin_amdgcn_mfma_f32_16x16x32_bf16(xh, wh3[2][s], a2, 0, 0, 0);
            a2  = __builtin_amdgcn_mfma_f32_16x16x32_bf16(xl, wh3[2][s], a2, 0, 0, 0);
            a2  = __builtin_amdgcn_mfma_f32_16x16x32_bf16(xh, wl3[2][s], a2, 0, 0, 0);
            a3v = __builtin_amdgcn_mfma_f32_16x16x32_bf16(xh, wh3[3][s], a3v, 0, 0, 0);
            a3v = __builtin_amdgcn_mfma_f32_16x16x32_bf16(xl, wh3[3][s], a3v, 0, 0, 0);
            a3v = __builtin_amdgcn_mfma_f32_16x16x32_bf16(xh, wl3[3][s], a3v, 0, 0, 0);

            xf[2 * s]     = *(const float4*)(xrn + k0);
            xf[2 * s + 1] = *(const float4*)(xrn + k0 + 4);
        }

        __syncthreads();   // previous iteration's combine reads are done
        #pragma unroll
        for (int r = 0; r < 4; ++r) {
            const int rr = (quad * 4 + r) * RPITCH + m;
            red3[0][wave][rr] = a0[r];
            red3[1][wave][rr] = a1[r];
            red3[2][wave][rr] = a2[r];
            red3[3][wave][rr] = a3v[r];
        }
        __syncthreads();

        #pragma unroll
        for (int c = 0; c < CGQ; ++c) {
            float z3 = 0.f;
            #pragma unroll
            for (int w = 0; w < 4; ++w)
                z3 += red3[c][w][row * RPITCH + col];
            ax[((size_t)t * B_ + grow) * H_ + (cg0 + c) * 16 + col] = z3;
        }
    }
}

// fast-path persistent kernel (round-6 proven version): per step only the
// h-dependent gates (72 MFMA); a-gate read from precomputed AX; block-level
// arrival on 8-way split counters.
__global__ __launch_bounds__(256, 1)
void plasdyn_persist_ax(const float* __restrict__ Bmu, const float* __restrict__ Bgmu,
                        const float* __restrict__ Bga, const float* __restrict__ Ba,
                        float* __restrict__ out, unsigned short* __restrict__ ws)
{
    __shared__ float red[4 * 3 * 16 * RPITCH];   // [wave][gate0..2][row][RPITCH]

    const int tid = threadIdx.x, bid = blockIdx.x;
    const int cg = bid & 63;
    const int colbase = cg * 16;
    const int rg = bid >> 6;
    const int rowbase = rg * 16;
    const int wave = tid >> 6, lane = tid & 63;
    const int m = lane & 15, quad = lane >> 4;
    const int kbase = wave * 256;

    unsigned* hpk = (unsigned*)(ws + WOFF_HPK);
    unsigned* syncp = (unsigned*)(ws + WOFF_SYNC);
    const float* ax = (const float*)(ws + WOFF_AX);

    // ---- one-time: stage gates 0..2 weight B-fragments in registers ----
    v8s wh[3][8], wl[3][8];
    #pragma unroll
    for (int g = 0; g < 3; ++g) {
        const unsigned short* ph = ws + WOFF_WHI + ((size_t)(g * 1024 + colbase + m) << 10) + kbase;
        const unsigned short* pl = ws + WOFF_WLO + ((size_t)(g * 1024 + colbase + m) << 10) + kbase;
        #pragma unroll
        for (int s = 0; s < 8; ++s) {
            wh[g][s] = *(const v8s*)(ph + s * 32 + quad * 8);
            wl[g][s] = *(const v8s*)(pl + s * 32 + quad * 8);
        }
    }

    const int row = tid >> 4, col = tid & 15;
    const int gcol = colbase + col;
    const int grow = rowbase + row;
    const float bmu = Bmu[gcol], bgmu = Bgmu[gcol], bga = Bga[gcol], ba = Ba[gcol];
    const int w_off = (((rg * 32 + (gcol >> 5)) * 4 + ((gcol >> 3) & 3)) * 16 + row) * 8 + (gcol & 7);
    const int fragbase_u32 = (rg * 32 + wave * 8) * 512 + lane * 8;

    unsigned* mycnt = &syncp[(rg * 8 + (cg & 7)) * 32];

    for (int t = 0; t < T_; ++t) {
        const int cur = t & 1, nxt = cur ^ 1;
        const unsigned long long* h64 = (const unsigned long long*)(hpk + cur * BH);

        // prefetch AX (precomputed; kernel-boundary coherence) — consumed in combine
        const float axv = ax[((size_t)t * B_ + grow) * H_ + gcol];

        // ---- release gate: all rg blocks published step t-1 ----
        if (t != 0) {
            if (tid == 0) {
                const unsigned target = 8u * (unsigned)t;
                for (;;) {
                    bool ok = true;
                    #pragma unroll
                    for (int c = 0; c < 8; ++c) {
                        unsigned v = __hip_atomic_load(&syncp[(rg * 8 + c) * 32],
                                                       __ATOMIC_RELAXED, __HIP_MEMORY_SCOPE_AGENT);
                        ok &= (v >= target);
                    }
                    if (ok) break;
                    __builtin_amdgcn_s_sleep(1);
                }
            }
            __syncthreads();
        }

        // ---- h-dependent gates (mu, gmu, ga) ----
        v4f acc0 = {0,0,0,0}, acc1 = {0,0,0,0}, acc2 = {0,0,0,0};

        #pragma unroll
        for (int s = 0; s < 8; ++s) {
            const int b64 = (fragbase_u32 + s * 512) >> 1;
            unsigned long long hq0 = __hip_atomic_load(h64 + b64 + 0, __ATOMIC_RELAXED, __HIP_MEMORY_SCOPE_AGENT);
            unsigned long long hq1 = __hip_atomic_load(h64 + b64 + 1, __ATOMIC_RELAXED, __HIP_MEMORY_SCOPE_AGENT);
            unsigned long long hq2 = __hip_atomic_load(h64 + b64 + 2, __ATOMIC_RELAXED, __HIP_MEMORY_SCOPE_AGENT);
            unsigned long long hq3 = __hip_atomic_load(h64 + b64 + 3, __ATOMIC_RELAXED, __HIP_MEMORY_SCOPE_AGENT);
            unsigned hu[8];
            hu[0] = (unsigned)hq0; hu[1] = (unsigned)(hq0 >> 32);
            hu[2] = (unsigned)hq1; hu[3] = (unsigned)(hq1 >> 32);
            hu[4] = (unsigned)hq2; hu[5] = (unsigned)(hq2 >> 32);
            hu[6] = (unsigned)hq3; hu[7] = (unsigned)(hq3 >> 32);
            v8s ahi, alo;
            #pragma unroll
            for (int j = 0; j < 8; ++j) {
                ahi[j] = (short)(hu[j] >> 16);
                alo[j] = (short)(hu[j] & 0xFFFFu);
            }

            acc0 = __builtin_amdgcn_mfma_f32_16x16x32_bf16(ahi, wh[0][s], acc0, 0, 0, 0);
            acc1 = __builtin_amdgcn_mfma_f32_16x16x32_bf16(ahi, wh[1][s], acc1, 0, 0, 0);
            acc2 = __builtin_amdgcn_mfma_f32_16x16x32_bf16(ahi, wh[2][s], acc2, 0, 0, 0);
            acc0 = __builtin_amdgcn_mfma_f32_16x16x32_bf16(alo, wh[0][s], acc0, 0, 0, 0);
            acc1 = __builtin_amdgcn_mfma_f32_16x16x32_bf16(alo, wh[1][s], acc1, 0, 0, 0);
            acc2 = __builtin_amdgcn_mfma_f32_16x16x32_bf16(alo, wh[2][s], acc2, 0, 0, 0);
            acc0 = __builtin_amdgcn_mfma_f32_16x16x32_bf16(ahi, wl[0][s], acc0, 0, 0, 0);
            acc1 = __builtin_amdgcn_mfma_f32_16x16x32_bf16(ahi, wl[1][s], acc1, 0, 0, 0);
            acc2 = __builtin_amdgcn_mfma_f32_16x16x32_bf16(ahi, wl[2][s], acc2, 0, 0, 0);
        }

        {
            float* rw = red + wave * (3 * 16 * RPITCH);
            #pragma unroll
            for (int r = 0; r < 4; ++r) {
                int rr = quad * 4 + r;
                rw[(0 * 16 + rr) * RPITCH + m] = acc0[r];
                rw[(1 * 16 + rr) * RPITCH + m] = acc1[r];
                rw[(2 * 16 + rr) * RPITCH + m] = acc2[r];
            }
        }
        __syncthreads();

        {
            float z0 = 0.f, z1 = 0.f, z2 = 0.f;
            #pragma unroll
            for (int w = 0; w < 4; ++w) {
                const float* rr = red + w * (3 * 16 * RPITCH);
                z0 += rr[(0 * 16 + row) * RPITCH + col];
                z1 += rr[(1 * 16 + row) * RPITCH + col];
                z2 += rr[(2 * 16 + row) * RPITCH + col];
            }
            float z3 = axv;   // computed identically in agate_pre
            z0 += bmu; z1 += bgmu; z2 += bga; z3 += ba;
            const float s1 = 1.0f / (1.0f + __expf(-z1));
            const float s2 = 1.0f / (1.0f + __expf(-z2));
            float hval = z0 * s1 + z3 * s2;
            hval = fminf(fmaxf(hval, -64.0f), 64.0f);   // NaN-squash safety

            const unsigned short hi16 = f2bf(hval);
            const unsigned short lo16 = f2bf(hval - bf2f(hi16));
            const unsigned pk = ((unsigned)hi16 << 16) | (unsigned)lo16;
            __hip_atomic_store(hpk + nxt * BH + w_off, pk,
                               __ATOMIC_RELAXED, __HIP_MEMORY_SCOPE_AGENT);
            if (t == T_ - 1) out[(size_t)grow * H_ + gcol] = hval;   // FP32 output
        }

        // drain h stores (vmcnt(0) in __syncthreads), then publish arrival.
        __syncthreads();
        if (t != T_ - 1 && tid == 0)
            __hip_atomic_fetch_add(mycnt, 1u, __ATOMIC_RELAXED, __HIP_MEMORY_SCOPE_AGENT);
    }
}

// ---------------- fallback (round-5 kernel, used if ws too small) ----------------
__global__ __launch_bounds__(256, 1)
void plasdyn_persist_fb(const float* __restrict__ xv,
                        const float* __restrict__ Bmu, const float* __restrict__ Bgmu,
                        const float* __restrict__ Bga, const float* __restrict__ Ba,
                        float* __restrict__ out, unsigned short* __restrict__ ws)
{
    __shared__ float red[4 * 3 * 16 * RPITCH];
    __shared__ float red3[4 * 16 * RPITCH];

    const int tid = threadIdx.x, bid = blockIdx.x;
    const int cg = bid & 63;
    const int colbase = cg * 16;
    const int rg = bid >> 6;
    const int rowbase = rg * 16;
    const int wave = tid >> 6, lane = tid & 63;
    const int m = lane & 15, quad = lane >> 4;
    const int kbase = wave * 256;
    const int rowm = rowbase + m;

    unsigned* hpk = (unsigned*)(ws + WOFF_HPK);
    unsigned* syncp = (unsigned*)(ws + WOFF_SYNC);

    v8s wh[4][8], wl[4][8];
    #pragma unroll
    for (int g = 0; g < 4; ++g) {
        const unsigned short* ph = ws + WOFF_WHI + ((size_t)(g * 1024 + colbase + m) << 10) + kbase;
        const unsigned short* pl = ws + WOFF_WLO + ((size_t)(g * 1024 + colbase + m) << 10) + kbase;
        #pragma unroll
        for (int s = 0; s < 8; ++s) {
            wh[g][s] = *(const v8s*)(ph + s * 32 + quad * 8);
            wl[g][s] = *(const v8s*)(pl + s * 32 + quad * 8);
        }
    }

    const int row = tid >> 4, col = tid & 15;
    const int gcol = colbase + col;
    const int grow = rowbase + row;
    const float bmu = Bmu[gcol], bgmu = Bgmu[gcol], bga = Bga[gcol], ba = Ba[gcol];
    const int w_off = (((rg * 32 + (gcol >> 5)) * 4 + ((gcol >> 3) & 3)) * 16 + row) * 8 + (gcol & 7);
    const int fragbase_u32 = (rg * 32 + wave * 8) * 512 + lane * 8;

    unsigned* mycnt = &syncp[(rg * 4 + (cg & 3)) * 32];
    unsigned* c0 = &syncp[(rg * 4 + 0) * 32];
    unsigned* c1 = &syncp[(rg * 4 + 1) * 32];
    unsigned* c2 = &syncp[(rg * 4 + 2) * 32];
    unsigned* c3 = &syncp[(rg * 4 + 3) * 32];

    float4 xf[16];
    auto phaseB = [&](const float* xrp) {
        v4f a3 = {0,0,0,0};
        #pragma unroll
        for (int s = 0; s < 8; ++s) {
            const int k0 = kbase + s * 32 + quad * 8;
            float4 f0 = xf[2 * s];
            float4 f1 = xf[2 * s + 1];
            float fv[8] = { f0.x, f0.y, f0.z, f0.w, f1.x, f1.y, f1.z, f1.w };
            v8s xh, xl;
            #pragma unroll
            for (int j = 0; j < 8; ++j) {
                unsigned short hb = f2bf(fv[j]);
                xh[j] = (short)hb;
                xl[j] = (short)f2bf(fv[j] - bf2f(hb));
            }
            a3 = __builtin_amdgcn_mfma_f32_16x16x32_bf16(xh, wh[3][s], a3, 0, 0, 0);
            a3 = __builtin_amdgcn_mfma_f32_16x16x32_bf16(xl, wh[3][s], a3, 0, 0, 0);
            a3 = __builtin_amdgcn_mfma_f32_16x16x32_bf16(xh, wl[3][s], a3, 0, 0, 0);
            xf[2 * s]     = *(const float4*)(xrp + k0);
            xf[2 * s + 1] = *(const float4*)(xrp + k0 + 4);
        }
        float* rw3 = red3 + wave * (16 * RPITCH);
        #pragma unroll
        for (int r = 0; r < 4; ++r)
            rw3[(quad * 4 + r) * RPITCH + m] = a3[r];
    };

    {
        const float* xr0 = xv + ((size_t)rowm * T_ + 0) * H_;
        #pragma unroll
        for (int s = 0; s < 8; ++s) {
            const int k0 = kbase + s * 32 + quad * 8;
            xf[2 * s]     = *(const float4*)(xr0 + k0);
            xf[2 * s + 1] = *(const float4*)(xr0 + k0 + 4);
        }
        const float* xr1 = xv + ((size_t)rowm * T_ + (T_ > 1 ? 1 : 0)) * H_;
        phaseB(xr1);
    }

    for (int t = 0; t < T_; ++t) {
        const int cur = t & 1, nxt = cur ^ 1;
        const unsigned long long* h64 = (const unsigned long long*)(hpk + cur * BH);

        if (t != 0) {
            if (tid == 0) {
                const unsigned target = 16u * (unsigned)t;
                for (;;) {
                    unsigned a = __hip_atomic_load(c0, __ATOMIC_RELAXED, __HIP_MEMORY_SCOPE_AGENT);
                    unsigned b = __hip_atomic_load(c1, __ATOMIC_RELAXED, __HIP_MEMORY_SCOPE_AGENT);
                    unsigned c = __hip_atomic_load(c2, __ATOMIC_RELAXED, __HIP_MEMORY_SCOPE_AGENT);
                    unsigned d = __hip_atomic_load(c3, __ATOMIC_RELAXED, __HIP_MEMORY_SCOPE_AGENT);
                    if (a >= target && b >= target && c >= target && d >= target) break;
                    __builtin_amdgcn_s_sleep(1);
                }
            }
            __syncthreads();
        }

        v4f acc0 = {0,0,0,0}, acc1 = {0,0,0,0}, acc2 = {0,0,0,0};

        #pragma unroll
        for (int s = 0; s < 8; ++s) {
            const int b64 = (fragbase_u32 + s * 512) >> 1;
            unsigned long long hq0 = __hip_atomic_load(h64 + b64 + 0, __ATOMIC_RELAXED, __HIP_MEMORY_SCOPE_AGENT);
            unsigned long long hq1 = __hip_atomic_load(h64 + b64 + 1, __ATOMIC_RELAXED, __HIP_MEMORY_SCOPE_AGENT);
            unsigned long long hq2 = __hip_atomic_load(h64 + b64 + 2, __ATOMIC_RELAXED, __HIP_MEMORY_SCOPE_AGENT);
            unsigned long long hq3 = __hip_atomic_load(h64 + b64 + 3, __ATOMIC_RELAXED, __HIP_MEMORY_SCOPE_AGENT);
            unsigned hu[8];
            hu[0] = (unsigned)hq0; hu[1] = (unsigned)(hq0 >> 32);
            hu[2] = (unsigned)hq1; hu[3] = (unsigned)(hq1 >> 32);
            hu[4] = (unsigned)hq2; hu[5] = (unsigned)(hq2 >> 32);
            hu[6] = (unsigned)hq3; hu[7] = (unsigned)(hq3 >> 32);
            v8s ahi, alo;
            #pragma unroll
            for (int j = 0; j < 8; ++j) {
                ahi[j] = (short)(hu[j] >> 16);
                alo[j] = (short)(hu[j] & 0xFFFFu);
            }

            acc0 = __builtin_amdgcn_mfma_f32_16x16x32_bf16(ahi, wh[0][s], acc0, 0, 0, 0);
            acc1 = __builtin_amdgcn_mfma_f32_16x16x32_bf16(ahi, wh[1][s], acc1, 0, 0, 0);
            acc2 = __builtin_amdgcn_mfma_f32_16x16x32_bf16(ahi, wh[2][s], acc2, 0, 0, 0);
            acc0 = __builtin_amdgcn_mfma_f32_16x16x32_bf16(alo, wh[0][s], acc0, 0, 0, 0);
            acc1 = __builtin_amdgcn_mfma_f32_16x16x32_bf16(alo, wh[1][s], acc1, 0, 0, 0);
            acc2 = __builtin_amdgcn_mfma_f32_16x16x32_bf16(alo, wh[2][s], acc2, 0, 0, 0);
            acc0 = __builtin_amdgcn_mfma_f32_16x16x32_bf16(ahi, wl[0][s], acc0, 0, 0, 0);
            acc1 = __builtin_amdgcn_mfma_f32_16x16x32_bf16(ahi, wl[1][s], acc1, 0, 0, 0);
            acc2 = __builtin_amdgcn_mfma_f32_16x16x32_bf16(ahi, wl[2][s], acc2, 0, 0, 0);
        }

        {
            float* rw = red + wave * (3 * 16 * RPITCH);
            #pragma unroll
            for (int r = 0; r < 4; ++r) {
                int rr = quad * 4 + r;
                rw[(0 * 16 + rr) * RPITCH + m] = acc0[r];
                rw[(1 * 16 + rr) * RPITCH + m] = acc1[r];
                rw[(2 * 16 + rr) * RPITCH + m] = acc2[r];
            }
        }
        __syncthreads();

        {
            float z0 = 0.f, z1 = 0.f, z2 = 0.f, z3 = 0.f;
            #pragma unroll
            for (int w = 0; w < 4; ++w) {
                const float* rr = red + w * (3 * 16 * RPITCH);
                z0 += rr[(0 * 16 + row) * RPITCH + col];
                z1 += rr[(1 * 16 + row) * RPITCH + col];
                z2 += rr[(2 * 16 + row) * RPITCH + col];
                z3 += red3[w * (16 * RPITCH) + row * RPITCH + col];
            }
            z0 += bmu; z1 += bgmu; z2 += bga; z3 += ba;
            const float s1 = 1.0f / (1.0f + __expf(-z1));
            const float s2 = 1.0f / (1.0f + __expf(-z2));
            float hval = z0 * s1 + z3 * s2;
            hval = fminf(fmaxf(hval, -64.0f), 64.0f);

            const unsigned short hi16 = f2bf(hval);
            const unsigned short lo16 = f2bf(hval - bf2f(hi16));
            const unsigned pk = ((unsigned)hi16 << 16) | (unsigned)lo16;
            __hip_atomic_store(hpk + nxt * BH + w_off, pk,
                               __ATOMIC_RELAXED, __HIP_MEMORY_SCOPE_AGENT);
            if (t == T_ - 1) out[(size_t)grow * H_ + gcol] = hval;
        }

        __syncthreads();
        if (t != T_ - 1) {
            if (tid == 0)
                __hip_atomic_fetch_add(mycnt, 1u, __ATOMIC_RELAXED, __HIP_MEMORY_SCOPE_AGENT);
            const int tp = (t + 2 < T_) ? (t + 2) : (T_ - 1);
            phaseB(xv + ((size_t)rowm * T_ + tp) * H_);
        }
    }
}

extern "C" void kernel_launch(void* const* d_in, const int* in_sizes, int n_in,
                              void* d_out, int out_size, void* d_ws, size_t ws_size,
                              hipStream_t stream)
{
    float* out = (float*)d_out;
    unsigned short* ws = (unsigned short*)d_ws;

    const int SZ_X = B_ * T_ * H_;
    const int SZ_W = H_ * H_;
    const int SZ_B = H_;

    bool dict_pat = (n_in == 9 &&
        in_sizes[0] == SZ_X &&
        in_sizes[1] == SZ_W && in_sizes[3] == SZ_W && in_sizes[5] == SZ_W && in_sizes[7] == SZ_W &&
        in_sizes[2] == SZ_B && in_sizes[4] == SZ_B && in_sizes[6] == SZ_B && in_sizes[8] == SZ_B);

    if (!dict_pat) {
        hipLaunchKernelGGL(sentinel_kernel, dim3((out_size + 255) / 256), dim3(256), 0, stream,
                           out, 2000.0f, out_size);
        return;
    }

    // dict order: x, W_mu, b_mu, Wg_mu, bg_mu, W_a, b_a, Wg_a, bg_a  (all fp32)
    const float* x    = (const float*)d_in[0];
    const float* Wmu  = (const float*)d_in[1];
    const float* bmu  = (const float*)d_in[2];
    const float* Wgmu = (const float*)d_in[3];
    const float* bgmu = (const float*)d_in[4];
    const float* Wa   = (const float*)d_in[5];
    const float* ba   = (const float*)d_in[6];
    const float* Wga  = (const float*)d_in[7];
    const float* bga  = (const float*)d_in[8];

    hipLaunchKernelGGL(conv_w_kernel, dim3(16384), dim3(256), 0, stream,
                       Wmu, Wgmu, Wga, Wa, ws);
    hipLaunchKernelGGL(init_h_kernel, dim3(256), dim3(256), 0, stream, ws);

    if (ws_size >= NEED_AX_BYTES) {
        hipLaunchKernelGGL(agate_pre, dim3(512), dim3(256), 0, stream, x, ws);
        hipLaunchKernelGGL(plasdyn_persist_ax, dim3(256), dim3(256), 0, stream,
                           bmu, bgmu, bga, ba, out, ws);
    } else {
        hipLaunchKernelGGL(plasdyn_persist_fb, dim3(256), dim3(256), 0, stream,
                           x, bmu, bgmu, bga, ba, out, ws);
    }
}